// Round 1
// baseline (694.128 us; speedup 1.0000x reference)
//
#include <hip/hip_runtime.h>

typedef unsigned short u16;
typedef u16 u16x8 __attribute__((ext_vector_type(8)));
typedef u16 u16x4 __attribute__((ext_vector_type(4)));
typedef float f32x4v __attribute__((ext_vector_type(4)));
typedef __bf16 bf16x8 __attribute__((ext_vector_type(8)));

// ---------- helpers ----------
__device__ __forceinline__ u16 f2bf(float f) {
  unsigned u = __builtin_bit_cast(unsigned, f);
  u += 0x7fffu + ((u >> 16) & 1u);  // round-to-nearest-even
  return (u16)(u >> 16);
}

// ---------- fp32 -> bf16 conversion (vectorized, memory-bound) ----------
__global__ __launch_bounds__(256) void cvt_f32_bf16(const float* __restrict__ in,
                                                    u16* __restrict__ out, long n) {
  long i0 = ((long)blockIdx.x * 256 + threadIdx.x) * 8;
  long stride = (long)gridDim.x * 256 * 8;
  for (long i = i0; i < n; i += stride) {
    float4 a = *(const float4*)(in + i);
    float4 b = *(const float4*)(in + i + 4);
    u16x8 o;
    o[0] = f2bf(a.x); o[1] = f2bf(a.y); o[2] = f2bf(a.z); o[3] = f2bf(a.w);
    o[4] = f2bf(b.x); o[5] = f2bf(b.y); o[6] = f2bf(b.z); o[7] = f2bf(b.w);
    *(u16x8*)(out + i) = o;
  }
}

// ---------- batched GEMM, A[M,K] row-major x B[N,K] row-major (B^T), 128x128 tile ----------
// EPI 0: C=f32 scores, val = mask ? acc*scale + 1e-13 : -1e-13
// EPI 1: C=bf16 plain
// EPI 2: C=f32 + bias[col]
template <int EPI>
__global__ __launch_bounds__(256, 2) void gemm_bt(
    const u16* __restrict__ A, long lda, long bsA,
    const u16* __restrict__ B, long ldb, long bsB,
    void* __restrict__ Cv, long ldc, long bsC, int K,
    const int* __restrict__ maskp, float scale,
    const float* __restrict__ bias) {
  __shared__ u16 sA[2][128 * 32];
  __shared__ u16 sB[2][128 * 32];
  const int t = threadIdx.x;
  const int lane = t & 63;
  const int w = t >> 6;            // wave 0..3, arranged 2x2 over the 128x128 tile
  const int wr = w >> 1, wc = w & 1;

  const u16* Ab = A + (long)blockIdx.z * bsA + (long)blockIdx.x * 128 * lda;
  const u16* Bb = B + (long)blockIdx.z * bsB + (long)blockIdx.y * 128 * ldb;
  // staging: thread t loads 16B chunks; chunk row = t>>2 (and +64), col8 = t&3
  const u16* ga = Ab + (long)(t >> 2) * lda + (t & 3) * 8;
  const u16* gb = Bb + (long)(t >> 2) * ldb + (t & 3) * 8;

  f32x4v acc[4][4];
#pragma unroll
  for (int i = 0; i < 4; ++i)
#pragma unroll
    for (int j = 0; j < 4; ++j) acc[i][j] = (f32x4v){0.f, 0.f, 0.f, 0.f};

  const int nk = K >> 5;  // BK = 32

#define STAGE(buf, k0)                                                                  \
  do {                                                                                  \
    __builtin_amdgcn_global_load_lds(                                                   \
        (const __attribute__((address_space(1))) void*)(ga + (k0)),                     \
        (__attribute__((address_space(3))) void*)(&sA[buf][t * 8]), 16, 0, 0);          \
    __builtin_amdgcn_global_load_lds(                                                   \
        (const __attribute__((address_space(1))) void*)(ga + (k0) + 64 * lda),          \
        (__attribute__((address_space(3))) void*)(&sA[buf][2048 + t * 8]), 16, 0, 0);   \
    __builtin_amdgcn_global_load_lds(                                                   \
        (const __attribute__((address_space(1))) void*)(gb + (k0)),                     \
        (__attribute__((address_space(3))) void*)(&sB[buf][t * 8]), 16, 0, 0);          \
    __builtin_amdgcn_global_load_lds(                                                   \
        (const __attribute__((address_space(1))) void*)(gb + (k0) + 64 * ldb),          \
        (__attribute__((address_space(3))) void*)(&sB[buf][2048 + t * 8]), 16, 0, 0);   \
  } while (0)

  STAGE(0, 0);
  __syncthreads();

  const int ar = lane & 15;          // row within 16-subtile (A/B operand row)
  const int aoff = (lane >> 4) * 8;  // k-offset of the 8 contiguous bf16
  int cur = 0;
  for (int kt = 0; kt < nk; ++kt) {
    if (kt + 1 < nk) STAGE(cur ^ 1, (kt + 1) * 32);
    bf16x8 af[4], bfr[4];
#pragma unroll
    for (int i = 0; i < 4; ++i) {
      af[i]  = *(const bf16x8*)&sA[cur][(wr * 64 + i * 16 + ar) * 32 + aoff];
      bfr[i] = *(const bf16x8*)&sB[cur][(wc * 64 + i * 16 + ar) * 32 + aoff];
    }
#pragma unroll
    for (int i = 0; i < 4; ++i)
#pragma unroll
      for (int j = 0; j < 4; ++j)
        acc[i][j] = __builtin_amdgcn_mfma_f32_16x16x32_bf16(af[i], bfr[j], acc[i][j], 0, 0, 0);
    __syncthreads();
    cur ^= 1;
  }
#undef STAGE

  // C/D layout (m89/m91 verified): col = lane&15, row = (lane>>4)*4 + reg
  const long row0 = (long)blockIdx.x * 128 + wr * 64;
  const long col0 = (long)blockIdx.y * 128 + wc * 64;
  const int l4 = lane >> 4;
  if constexpr (EPI == 0) {
    float* C = (float*)Cv + (long)blockIdx.z * bsC;
    const int* mrow = maskp + (long)blockIdx.z * 2048;
#pragma unroll
    for (int j = 0; j < 4; ++j) {
      long col = col0 + j * 16 + ar;
      int mk = mrow[col];
#pragma unroll
      for (int i = 0; i < 4; ++i) {
        long row = row0 + i * 16 + l4 * 4;
#pragma unroll
        for (int r = 0; r < 4; ++r) {
          float v = mk ? acc[i][j][r] * scale + 1e-13f : -1e-13f;
          C[(row + r) * ldc + col] = v;
        }
      }
    }
  } else if constexpr (EPI == 1) {
    u16* C = (u16*)Cv + (long)blockIdx.z * bsC;
#pragma unroll
    for (int j = 0; j < 4; ++j) {
      long col = col0 + j * 16 + ar;
#pragma unroll
      for (int i = 0; i < 4; ++i) {
        long row = row0 + i * 16 + l4 * 4;
#pragma unroll
        for (int r = 0; r < 4; ++r) C[(row + r) * ldc + col] = f2bf(acc[i][j][r]);
      }
    }
  } else {
    float* C = (float*)Cv;
#pragma unroll
    for (int j = 0; j < 4; ++j) {
      long col = col0 + j * 16 + ar;
      float bj = bias[col];
#pragma unroll
      for (int i = 0; i < 4; ++i) {
        long row = row0 + i * 16 + l4 * 4;
#pragma unroll
        for (int r = 0; r < 4; ++r) C[(row + r) * ldc + col] = acc[i][j][r] + bj;
      }
    }
  }
}

// ---------- row softmax: read 2048 f32, write 2048 bf16 in-place (row stride 8192B) ----------
__global__ __launch_bounds__(256) void softmax_rows(float* __restrict__ S) {
  const int t = threadIdx.x;
  const float* row = S + (long)blockIdx.x * 2048;
  float4 x0 = ((const float4*)row)[t];        // elements 4t..4t+3
  float4 x1 = ((const float4*)row)[256 + t];  // elements 1024+4t..
  float m = fmaxf(fmaxf(fmaxf(x0.x, x0.y), fmaxf(x0.z, x0.w)),
                  fmaxf(fmaxf(x1.x, x1.y), fmaxf(x1.z, x1.w)));
#pragma unroll
  for (int off = 32; off; off >>= 1) m = fmaxf(m, __shfl_xor(m, off));
  __shared__ float red[8];
  if ((t & 63) == 0) red[t >> 6] = m;
  __syncthreads();
  m = fmaxf(fmaxf(red[0], red[1]), fmaxf(red[2], red[3]));
  float p[8];
  p[0] = __expf(x0.x - m); p[1] = __expf(x0.y - m);
  p[2] = __expf(x0.z - m); p[3] = __expf(x0.w - m);
  p[4] = __expf(x1.x - m); p[5] = __expf(x1.y - m);
  p[6] = __expf(x1.z - m); p[7] = __expf(x1.w - m);
  float s = ((p[0] + p[1]) + (p[2] + p[3])) + ((p[4] + p[5]) + (p[6] + p[7]));
#pragma unroll
  for (int off = 32; off; off >>= 1) s += __shfl_xor(s, off);
  if ((t & 63) == 0) red[4 + (t >> 6)] = s;
  __syncthreads();
  float inv = 1.0f / (red[4] + red[5] + red[6] + red[7]);
  u16* prow = (u16*)S + (long)blockIdx.x * 4096;  // bf16 row inside the f32 row's bytes
  u16x4 o0, o1;
  o0[0] = f2bf(p[0] * inv); o0[1] = f2bf(p[1] * inv);
  o0[2] = f2bf(p[2] * inv); o0[3] = f2bf(p[3] * inv);
  o1[0] = f2bf(p[4] * inv); o1[1] = f2bf(p[5] * inv);
  o1[2] = f2bf(p[6] * inv); o1[3] = f2bf(p[7] * inv);
  *(u16x4*)(prow + 4 * t) = o0;
  *(u16x4*)(prow + 1024 + 4 * t) = o1;
}

// ---------- launcher ----------
extern "C" void kernel_launch(void* const* d_in, const int* in_sizes, int n_in,
                              void* d_out, int out_size, void* d_ws, size_t ws_size,
                              hipStream_t stream) {
  const float* Q = (const float*)d_in[0];
  const float* K = (const float*)d_in[1];
  const float* V = (const float*)d_in[2];
  const int* mask = (const int*)d_in[3];
  const float* W = (const float*)d_in[4];
  const float* bias = (const float*)d_in[5];

  const long NQ = 16L * 2048 * 1024;  // 33,554,432 elements
  u16* Qb = (u16*)d_ws;
  u16* Kb = Qb + NQ;
  u16* Vb = Kb + NQ;
  u16* Wb = Vb + NQ;                        // 1024*1024
  float* S = (float*)(Wb + 1024L * 1024);   // [16][2048][2048] f32, P bf16 in-place
  u16* R = Qb;                              // alias: Qb dead after GEMM1

  cvt_f32_bf16<<<2048, 256, 0, stream>>>(Q, Qb, NQ);
  cvt_f32_bf16<<<2048, 256, 0, stream>>>(K, Kb, NQ);
  cvt_f32_bf16<<<2048, 256, 0, stream>>>(V, Vb, NQ);
  cvt_f32_bf16<<<512, 256, 0, stream>>>(W, Wb, 1024L * 1024);

  // S = Q Kt * scale (+1e-13), masked cols -> -1e-13   [M=2048, N=2048, K=1024]
  gemm_bt<0><<<dim3(16, 16, 16), 256, 0, stream>>>(
      Qb, 1024, 2048L * 1024, Kb, 1024, 2048L * 1024,
      S, 2048, 2048L * 2048, 1024, mask, 0.03125f, nullptr);

  softmax_rows<<<32768, 256, 0, stream>>>(S);

  // R = P Vt   [M=2048, N=1024, K=2048], P has lda 4096 (bf16 inside f32 rows)
  gemm_bt<1><<<dim3(16, 8, 16), 256, 0, stream>>>(
      (const u16*)S, 4096, 2048L * 4096, Vb, 2048, 1024L * 2048,
      R, 1024, 2048L * 1024, 2048, nullptr, 1.f, nullptr);

  // out = R Wt + bias   [M=32768, N=1024, K=1024]
  gemm_bt<2><<<dim3(256, 8, 1), 256, 0, stream>>>(
      R, 1024, 0, Wb, 1024, 0,
      d_out, 1024, 0, 1024, nullptr, 1.f, bias);
}

// Round 2
// 642.723 us; speedup vs baseline: 1.0800x; 1.0800x over previous
//
#include <hip/hip_runtime.h>

typedef unsigned short u16;
typedef u16 u16x8 __attribute__((ext_vector_type(8)));
typedef u16 u16x4 __attribute__((ext_vector_type(4)));
typedef float f32x4v __attribute__((ext_vector_type(4)));
typedef __bf16 bf16x8 __attribute__((ext_vector_type(8)));

// ---------- helpers ----------
__device__ __forceinline__ u16 f2bf(float f) {
  unsigned u = __builtin_bit_cast(unsigned, f);
  u += 0x7fffu + ((u >> 16) & 1u);  // round-to-nearest-even
  return (u16)(u >> 16);
}

// ---------- fp32 -> bf16 conversion ----------
__global__ __launch_bounds__(256) void cvt_f32_bf16(const float* __restrict__ in,
                                                    u16* __restrict__ out, long n) {
  long i0 = ((long)blockIdx.x * 256 + threadIdx.x) * 8;
  long stride = (long)gridDim.x * 256 * 8;
  for (long i = i0; i < n; i += stride) {
    float4 a = *(const float4*)(in + i);
    float4 b = *(const float4*)(in + i + 4);
    u16x8 o;
    o[0] = f2bf(a.x); o[1] = f2bf(a.y); o[2] = f2bf(a.z); o[3] = f2bf(a.w);
    o[4] = f2bf(b.x); o[5] = f2bf(b.y); o[6] = f2bf(b.z); o[7] = f2bf(b.w);
    *(u16x8*)(out + i) = o;
  }
}

// ---------- 256x256 GEMM, A[M,K] x B[N,K]^T, BK=64, 8 waves, counted-vmcnt pipeline ----------
// LDS (dynamic, 128 KiB): shA[p][ks] = sm + (p*2+ks)*8192 u16   ([256 rows][32 cols] bf16, dense)
//                         shB[p][ks] = sm + 32768 + (p*2+ks)*8192
// Swizzle: 16B chunk c of row stored holding global chunk c ^ ((row>>1)&3)  (involution).
// Schedule per K-tile t (buf p=t&1):
//   ph1: issue A1B1(t+1); ds_read ks0; MFMA x32; vmcnt(8|0); barrier
//   ph2: issue A0B0(t+2); ds_read ks1; MFMA x32; vmcnt(8|4|0); barrier
// Dependency proof: group G(t+2) staged into slot last READ at the phase 2 barriers earlier;
// vmcnt(8) = loads issued after the target group (2 groups x 4) -> target landed; barrier
// publishes LDS to all waves before the dependent ds_reads next phase.
template <int EPI>
__global__ __launch_bounds__(512, 2) void gemm256(
    const u16* __restrict__ A, long lda, long bsA,
    const u16* __restrict__ B, long ldb, long bsB,
    void* __restrict__ Cv, long ldc, long bsC, int K,
    const int* __restrict__ maskp, float scale,
    const float* __restrict__ bias) {
  extern __shared__ u16 sm[];
  const int t = threadIdx.x;
  const int lane = t & 63;
  const int w = t >> 6;    // 0..7
  const int wr = w >> 2;   // 0..1 : 128-row group
  const int wc = w & 3;    // 0..3 : 64-col group

  const u16* Ab = A + (long)blockIdx.z * bsA + (long)blockIdx.x * 256 * lda;
  const u16* Bb = B + (long)blockIdx.z * bsB + (long)blockIdx.y * 256 * ldb;

  // staging: thread t covers rows (t>>2) and (t>>2)+128, 16B chunk (t&3), source-swizzled
  const int srow = t >> 2;
  const int scw = ((t & 3) ^ ((srow >> 1) & 3)) * 8;  // swizzled k-chunk offset (u16)
  const u16* gA = Ab + (long)srow * lda + scw;
  const u16* gB = Bb + (long)srow * ldb + scw;
  const long a128 = 128 * lda, b128 = 128 * ldb;

#define GLDS(gptr, lidx)                                                        \
  __builtin_amdgcn_global_load_lds(                                             \
      (const __attribute__((address_space(1))) void*)(gptr),                    \
      (__attribute__((address_space(3))) void*)(sm + (lidx)), 16, 0, 0)

#define STAGE(p, ks, kt)                                                        \
  do {                                                                          \
    long ko = (long)(kt)*64 + (ks)*32;                                          \
    GLDS(gA + ko,        ((p)*2 + (ks)) * 8192 + t * 8);                        \
    GLDS(gA + ko + a128, ((p)*2 + (ks)) * 8192 + t * 8 + 4096);                 \
    GLDS(gB + ko,        32768 + ((p)*2 + (ks)) * 8192 + t * 8);                \
    GLDS(gB + ko + b128, 32768 + ((p)*2 + (ks)) * 8192 + t * 8 + 4096);         \
  } while (0)

  f32x4v acc[8][4];
#pragma unroll
  for (int i = 0; i < 8; ++i)
#pragma unroll
    for (int j = 0; j < 4; ++j) acc[i][j] = (f32x4v){0.f, 0.f, 0.f, 0.f};

  // ds_read fragment addressing (swizzle XOR term invariant across fr/fc)
  const int rA = wr * 128 + (lane & 15);
  const int rB = wc * 64 + (lane & 15);
  const int aoff = rA * 32 + (((lane >> 4) ^ ((rA >> 1) & 3)) * 8);
  const int boff = rB * 32 + (((lane >> 4) ^ ((rB >> 1) & 3)) * 8);

#define COMPUTE(p, ks)                                                          \
  do {                                                                          \
    const u16* baA = sm + ((p)*2 + (ks)) * 8192;                                \
    const u16* baB = sm + 32768 + ((p)*2 + (ks)) * 8192;                        \
    bf16x8 af[8], bq[4];                                                        \
    _Pragma("unroll") for (int fc = 0; fc < 4; ++fc)                            \
        bq[fc] = *(const bf16x8*)(baB + boff + fc * 512);                       \
    _Pragma("unroll") for (int fr = 0; fr < 8; ++fr)                            \
        af[fr] = *(const bf16x8*)(baA + aoff + fr * 512);                       \
    __builtin_amdgcn_s_setprio(1);                                              \
    _Pragma("unroll") for (int fr = 0; fr < 8; ++fr)                            \
        _Pragma("unroll") for (int fc = 0; fc < 4; ++fc)                        \
            acc[fr][fc] = __builtin_amdgcn_mfma_f32_16x16x32_bf16(              \
                af[fr], bq[fc], acc[fr][fc], 0, 0, 0);                          \
    __builtin_amdgcn_s_setprio(0);                                              \
  } while (0)

  const int nt = K >> 6;

  // prologue: A0B0(0), A1B1(0), A0B0(1); drain to 8 -> G1 landed
  STAGE(0, 0, 0);
  STAGE(0, 1, 0);
  if (nt > 1) STAGE(1, 0, 1);
  asm volatile("s_waitcnt vmcnt(8)" ::: "memory");
  __builtin_amdgcn_s_barrier();

  for (int kt = 0; kt < nt; ++kt) {
    const int p = kt & 1;
    // ---- phase 1 : ks = 0 ----
    if (kt + 1 < nt) STAGE(p ^ 1, 1, kt + 1);
    COMPUTE(p, 0);
    if (kt + 1 < nt)
      asm volatile("s_waitcnt vmcnt(8)" ::: "memory");
    else
      asm volatile("s_waitcnt vmcnt(0)" ::: "memory");
    __builtin_amdgcn_s_barrier();
    // ---- phase 2 : ks = 1 ----
    if (kt + 2 < nt) STAGE(p, 0, kt + 2);
    COMPUTE(p, 1);
    if (kt + 2 < nt)
      asm volatile("s_waitcnt vmcnt(8)" ::: "memory");
    else if (kt + 1 < nt)
      asm volatile("s_waitcnt vmcnt(4)" ::: "memory");
    else
      asm volatile("s_waitcnt vmcnt(0)" ::: "memory");
    __builtin_amdgcn_s_barrier();
  }
#undef STAGE
#undef GLDS
#undef COMPUTE

  // ---- epilogue: C/D layout col = lane&15, row = (lane>>4)*4 + reg ----
  const long row0 = (long)blockIdx.x * 256 + wr * 128;
  const long col0 = (long)blockIdx.y * 256 + wc * 64;
  const int l4 = lane >> 4;
  const int cl = lane & 15;
  if constexpr (EPI == 0) {
    float* C = (float*)Cv + (long)blockIdx.z * bsC;
    const int* mrow = maskp + (long)blockIdx.z * 2048;
#pragma unroll
    for (int fc = 0; fc < 4; ++fc) {
      long col = col0 + fc * 16 + cl;
      int mk = mrow[col];
#pragma unroll
      for (int fr = 0; fr < 8; ++fr) {
        long row = row0 + fr * 16 + l4 * 4;
#pragma unroll
        for (int r = 0; r < 4; ++r) {
          float v = mk ? acc[fr][fc][r] * scale + 1e-13f : -1e-13f;
          C[(row + r) * ldc + col] = v;
        }
      }
    }
  } else if constexpr (EPI == 1) {
    u16* C = (u16*)Cv + (long)blockIdx.z * bsC;
#pragma unroll
    for (int fc = 0; fc < 4; ++fc) {
      long col = col0 + fc * 16 + cl;
#pragma unroll
      for (int fr = 0; fr < 8; ++fr) {
        long row = row0 + fr * 16 + l4 * 4;
#pragma unroll
        for (int r = 0; r < 4; ++r) C[(row + r) * ldc + col] = f2bf(acc[fr][fc][r]);
      }
    }
  } else {
    float* C = (float*)Cv;
#pragma unroll
    for (int fc = 0; fc < 4; ++fc) {
      long col = col0 + fc * 16 + cl;
      float bj = bias[col];
#pragma unroll
      for (int fr = 0; fr < 8; ++fr) {
        long row = row0 + fr * 16 + l4 * 4;
#pragma unroll
        for (int r = 0; r < 4; ++r) C[(row + r) * ldc + col] = acc[fr][fc][r] + bj;
      }
    }
  }
}

// ---------- row softmax: read 2048 f32, write 2048 bf16 in-place ----------
__global__ __launch_bounds__(256) void softmax_rows(float* __restrict__ S) {
  const int t = threadIdx.x;
  const float* row = S + (long)blockIdx.x * 2048;
  float4 x0 = ((const float4*)row)[t];
  float4 x1 = ((const float4*)row)[256 + t];
  float m = fmaxf(fmaxf(fmaxf(x0.x, x0.y), fmaxf(x0.z, x0.w)),
                  fmaxf(fmaxf(x1.x, x1.y), fmaxf(x1.z, x1.w)));
#pragma unroll
  for (int off = 32; off; off >>= 1) m = fmaxf(m, __shfl_xor(m, off));
  __shared__ float red[8];
  if ((t & 63) == 0) red[t >> 6] = m;
  __syncthreads();
  m = fmaxf(fmaxf(red[0], red[1]), fmaxf(red[2], red[3]));
  float p[8];
  p[0] = __expf(x0.x - m); p[1] = __expf(x0.y - m);
  p[2] = __expf(x0.z - m); p[3] = __expf(x0.w - m);
  p[4] = __expf(x1.x - m); p[5] = __expf(x1.y - m);
  p[6] = __expf(x1.z - m); p[7] = __expf(x1.w - m);
  float s = ((p[0] + p[1]) + (p[2] + p[3])) + ((p[4] + p[5]) + (p[6] + p[7]));
#pragma unroll
  for (int off = 32; off; off >>= 1) s += __shfl_xor(s, off);
  if ((t & 63) == 0) red[4 + (t >> 6)] = s;
  __syncthreads();
  float inv = 1.0f / (red[4] + red[5] + red[6] + red[7]);
  u16* prow = (u16*)S + (long)blockIdx.x * 4096;
  u16x4 o0, o1;
  o0[0] = f2bf(p[0] * inv); o0[1] = f2bf(p[1] * inv);
  o0[2] = f2bf(p[2] * inv); o0[3] = f2bf(p[3] * inv);
  o1[0] = f2bf(p[4] * inv); o1[1] = f2bf(p[5] * inv);
  o1[2] = f2bf(p[6] * inv); o1[3] = f2bf(p[7] * inv);
  *(u16x4*)(prow + 4 * t) = o0;
  *(u16x4*)(prow + 1024 + 4 * t) = o1;
}

// ---------- launcher ----------
extern "C" void kernel_launch(void* const* d_in, const int* in_sizes, int n_in,
                              void* d_out, int out_size, void* d_ws, size_t ws_size,
                              hipStream_t stream) {
  const float* Q = (const float*)d_in[0];
  const float* K = (const float*)d_in[1];
  const float* V = (const float*)d_in[2];
  const int* mask = (const int*)d_in[3];
  const float* W = (const float*)d_in[4];
  const float* bias = (const float*)d_in[5];

  const long NQ = 16L * 2048 * 1024;
  u16* Qb = (u16*)d_ws;
  u16* Kb = Qb + NQ;
  u16* Vb = Kb + NQ;
  u16* Wb = Vb + NQ;
  float* S = (float*)(Wb + 1024L * 1024);  // [16][2048][2048] f32; P bf16 in-place
  u16* R = Qb;                             // alias: Qb dead after GEMM1

  cvt_f32_bf16<<<2048, 256, 0, stream>>>(Q, Qb, NQ);
  cvt_f32_bf16<<<2048, 256, 0, stream>>>(K, Kb, NQ);
  cvt_f32_bf16<<<2048, 256, 0, stream>>>(V, Vb, NQ);
  cvt_f32_bf16<<<512, 256, 0, stream>>>(W, Wb, 1024L * 1024);

  // S = QK^T * scale (+1e-13), masked cols -> -1e-13   [2048 x 2048 x 1024] x16
  gemm256<0><<<dim3(8, 8, 16), 512, 131072, stream>>>(
      Qb, 1024, 2048L * 1024, Kb, 1024, 2048L * 1024,
      S, 2048, 2048L * 2048, 1024, mask, 0.03125f, nullptr);

  softmax_rows<<<32768, 256, 0, stream>>>(S);

  // R = P V^T   [2048 x 1024 x 2048] x16 ; P lda 4096 (bf16 inside f32 rows)
  gemm256<1><<<dim3(8, 4, 16), 512, 131072, stream>>>(
      (const u16*)S, 4096, 2048L * 4096, Vb, 2048, 1024L * 2048,
      R, 1024, 2048L * 1024, 2048, nullptr, 1.f, nullptr);

  // out = R W^T + bias   [32768 x 1024 x 1024]
  gemm256<2><<<dim3(128, 4, 1), 512, 131072, stream>>>(
      R, 1024, 0, Wb, 1024, 0,
      d_out, 1024, 0, 1024, nullptr, 1.f, bias);
}

// Round 3
// 632.196 us; speedup vs baseline: 1.0980x; 1.0167x over previous
//
#include <hip/hip_runtime.h>

typedef unsigned short u16;
typedef u16 u16x8 __attribute__((ext_vector_type(8)));
typedef u16 u16x4 __attribute__((ext_vector_type(4)));
typedef float f32x4v __attribute__((ext_vector_type(4)));
typedef __bf16 bf16x8 __attribute__((ext_vector_type(8)));

// ---------- helpers ----------
__device__ __forceinline__ u16 f2bf(float f) {
  unsigned u = __builtin_bit_cast(unsigned, f);
  u += 0x7fffu + ((u >> 16) & 1u);  // round-to-nearest-even
  return (u16)(u >> 16);
}

// ---------- fp32 -> bf16 conversion ----------
__global__ __launch_bounds__(256) void cvt_f32_bf16(const float* __restrict__ in,
                                                    u16* __restrict__ out, long n) {
  long i0 = ((long)blockIdx.x * 256 + threadIdx.x) * 8;
  long stride = (long)gridDim.x * 256 * 8;
  for (long i = i0; i < n; i += stride) {
    float4 a = *(const float4*)(in + i);
    float4 b = *(const float4*)(in + i + 4);
    u16x8 o;
    o[0] = f2bf(a.x); o[1] = f2bf(a.y); o[2] = f2bf(a.z); o[3] = f2bf(a.w);
    o[4] = f2bf(b.x); o[5] = f2bf(b.y); o[6] = f2bf(b.z); o[7] = f2bf(b.w);
    *(u16x8*)(out + i) = o;
  }
}

// ---------- 256x256 GEMM, A[M,K] x B[N,K]^T, BK=64, 8 waves, 4-phase/K-tile ----------
// LDS (128 KiB): shA[p][ks] = sm + (p*2+ks)*8192   ([256 rows][32 k] bf16 dense, swizzled)
//                shB[p][ks] = sm + 32768 + (p*2+ks)*8192
// Swizzle: 16B chunk c of row r holds global chunk c ^ ((r>>1)&3)  (involution).
// Per K-tile t (buf p=t&1), 4 phases; phase = (ks, fr-half h):
//   pre-barrier: ds_read frags (8 b128 if h==0 else 4) ; issue stage piece of tile t+1
//   s_barrier ; lgkmcnt(0) ; setprio(1) ; 16 MFMA ; setprio(0) ; [vmcnt] ; s_barrier
// Stage pieces (2 gloads each): ph1->A(ks0), ph2->B(ks0), ph3->A(ks1), ph4->B(ks1).
// vmcnt proof (FIFO): end-ph2 outstanding = {t:A1,B1, t+1:A0,B0} = 8 -> vmcnt(4) waits
// oldest 4 = this tile's ks1 pieces (read in ph3/4). End-ph4 outstanding = {t+1:A0,B0,A1,B1}
// = 8 -> vmcnt(4) waits next tile's ks0 pieces (read in next ph1/2). Tails get vmcnt(0).
template <int EPI>
__global__ __launch_bounds__(512, 2) void gemm256(
    const u16* __restrict__ A, long lda, long bsA,
    const u16* __restrict__ B, long ldb, long bsB,
    void* __restrict__ Cv, long ldc, long bsC, int K,
    const int* __restrict__ maskp, float scale,
    const float* __restrict__ bias) {
  extern __shared__ u16 sm[];
  const int t = threadIdx.x;
  const int lane = t & 63;
  const int w = t >> 6;
  const int wr = w >> 2;   // 0..1 : 128-row group
  const int wc = w & 3;    // 0..3 : 64-col group

  const u16* Ab = A + (long)blockIdx.z * bsA + (long)blockIdx.x * 256 * lda;
  const u16* Bb = B + (long)blockIdx.z * bsB + (long)blockIdx.y * 256 * ldb;

  const int srow = t >> 2;
  const int scw = ((t & 3) ^ ((srow >> 1) & 3)) * 8;  // source-swizzled k-chunk (u16)
  const u16* gA = Ab + (long)srow * lda + scw;
  const u16* gB = Bb + (long)srow * ldb + scw;
  const long a128 = 128 * lda, b128 = 128 * ldb;

#define GLDS(gptr, lidx)                                                        \
  __builtin_amdgcn_global_load_lds(                                             \
      (const __attribute__((address_space(1))) void*)(gptr),                    \
      (__attribute__((address_space(3))) void*)(sm + (lidx)), 16, 0, 0)

// piece: 0=A(ks0) 1=B(ks0) 2=A(ks1) 3=B(ks1); 2 gloads each
#define STAGE_P(p, piece, kt)                                                   \
  do {                                                                          \
    const int ks_ = (piece) >> 1;                                               \
    long ko = (long)(kt)*64 + ks_ * 32;                                         \
    if (((piece)&1) == 0) {                                                     \
      GLDS(gA + ko,        ((p)*2 + ks_) * 8192 + t * 8);                       \
      GLDS(gA + ko + a128, ((p)*2 + ks_) * 8192 + t * 8 + 4096);                \
    } else {                                                                    \
      GLDS(gB + ko,        32768 + ((p)*2 + ks_) * 8192 + t * 8);               \
      GLDS(gB + ko + b128, 32768 + ((p)*2 + ks_) * 8192 + t * 8 + 4096);        \
    }                                                                           \
  } while (0)

  f32x4v acc[8][4];
#pragma unroll
  for (int i = 0; i < 8; ++i)
#pragma unroll
    for (int j = 0; j < 4; ++j) acc[i][j] = (f32x4v){0.f, 0.f, 0.f, 0.f};

  const int rA0 = wr * 128 + (lane & 15);
  const int rB0 = wc * 64 + (lane & 15);
  const int aoff = rA0 * 32 + (((lane >> 4) ^ ((rA0 >> 1) & 3)) * 8);
  const int boff = rB0 * 32 + (((lane >> 4) ^ ((rB0 >> 1) & 3)) * 8);

  const int nt = K >> 6;

  // prologue: all 4 pieces of tile 0 -> buf 0; ks0 pieces landed before loop
  STAGE_P(0, 0, 0);
  STAGE_P(0, 1, 0);
  STAGE_P(0, 2, 0);
  STAGE_P(0, 3, 0);
  asm volatile("s_waitcnt vmcnt(4)" ::: "memory");
  __builtin_amdgcn_s_barrier();

  for (int kt = 0; kt < nt; ++kt) {
    const int p = kt & 1;
    const bool nx = (kt + 1 < nt);
    const u16* baA0 = sm + (p * 2 + 0) * 8192;
    const u16* baB0 = sm + 32768 + (p * 2 + 0) * 8192;
    const u16* baA1 = sm + (p * 2 + 1) * 8192;
    const u16* baB1 = sm + 32768 + (p * 2 + 1) * 8192;
    bf16x8 af[4], bq[4];

    // ---- phase 1: ks0, fr 0..3 ----
#pragma unroll
    for (int i = 0; i < 4; ++i) af[i] = *(const bf16x8*)(baA0 + aoff + i * 512);
#pragma unroll
    for (int fc = 0; fc < 4; ++fc) bq[fc] = *(const bf16x8*)(baB0 + boff + fc * 512);
    if (nx) STAGE_P(p ^ 1, 0, kt + 1);
    __builtin_amdgcn_s_barrier();
    asm volatile("s_waitcnt lgkmcnt(0)" ::: "memory");
    __builtin_amdgcn_s_setprio(1);
#pragma unroll
    for (int i = 0; i < 4; ++i)
#pragma unroll
      for (int fc = 0; fc < 4; ++fc)
        acc[i][fc] = __builtin_amdgcn_mfma_f32_16x16x32_bf16(af[i], bq[fc], acc[i][fc], 0, 0, 0);
    __builtin_amdgcn_s_setprio(0);
    __builtin_amdgcn_s_barrier();

    // ---- phase 2: ks0, fr 4..7 ----
#pragma unroll
    for (int i = 0; i < 4; ++i) af[i] = *(const bf16x8*)(baA0 + aoff + (4 + i) * 512);
    if (nx) STAGE_P(p ^ 1, 1, kt + 1);
    __builtin_amdgcn_s_barrier();
    asm volatile("s_waitcnt lgkmcnt(0)" ::: "memory");
    __builtin_amdgcn_s_setprio(1);
#pragma unroll
    for (int i = 0; i < 4; ++i)
#pragma unroll
      for (int fc = 0; fc < 4; ++fc)
        acc[4 + i][fc] = __builtin_amdgcn_mfma_f32_16x16x32_bf16(af[i], bq[fc], acc[4 + i][fc], 0, 0, 0);
    __builtin_amdgcn_s_setprio(0);
    if (nx)
      asm volatile("s_waitcnt vmcnt(4)" ::: "memory");
    else
      asm volatile("s_waitcnt vmcnt(0)" ::: "memory");
    __builtin_amdgcn_s_barrier();

    // ---- phase 3: ks1, fr 0..3 ----
#pragma unroll
    for (int i = 0; i < 4; ++i) af[i] = *(const bf16x8*)(baA1 + aoff + i * 512);
#pragma unroll
    for (int fc = 0; fc < 4; ++fc) bq[fc] = *(const bf16x8*)(baB1 + boff + fc * 512);
    if (nx) STAGE_P(p ^ 1, 2, kt + 1);
    __builtin_amdgcn_s_barrier();
    asm volatile("s_waitcnt lgkmcnt(0)" ::: "memory");
    __builtin_amdgcn_s_setprio(1);
#pragma unroll
    for (int i = 0; i < 4; ++i)
#pragma unroll
      for (int fc = 0; fc < 4; ++fc)
        acc[i][fc] = __builtin_amdgcn_mfma_f32_16x16x32_bf16(af[i], bq[fc], acc[i][fc], 0, 0, 0);
    __builtin_amdgcn_s_setprio(0);
    __builtin_amdgcn_s_barrier();

    // ---- phase 4: ks1, fr 4..7 ----
#pragma unroll
    for (int i = 0; i < 4; ++i) af[i] = *(const bf16x8*)(baA1 + aoff + (4 + i) * 512);
    if (nx) STAGE_P(p ^ 1, 3, kt + 1);
    __builtin_amdgcn_s_barrier();
    asm volatile("s_waitcnt lgkmcnt(0)" ::: "memory");
    __builtin_amdgcn_s_setprio(1);
#pragma unroll
    for (int i = 0; i < 4; ++i)
#pragma unroll
      for (int fc = 0; fc < 4; ++fc)
        acc[4 + i][fc] = __builtin_amdgcn_mfma_f32_16x16x32_bf16(af[i], bq[fc], acc[4 + i][fc], 0, 0, 0);
    __builtin_amdgcn_s_setprio(0);
    if (nx)
      asm volatile("s_waitcnt vmcnt(4)" ::: "memory");
    __builtin_amdgcn_s_barrier();
  }
#undef STAGE_P
#undef GLDS

  // ---- epilogue: C/D layout col = lane&15, row = (lane>>4)*4 + reg ----
  const long row0 = (long)blockIdx.x * 256 + wr * 128;
  const long col0 = (long)blockIdx.y * 256 + wc * 64;
  const int l4 = lane >> 4;
  const int cl = lane & 15;
  if constexpr (EPI == 0) {
    float* C = (float*)Cv + (long)blockIdx.z * bsC;
    const int* mrow = maskp + (long)blockIdx.z * 2048;
#pragma unroll
    for (int fc = 0; fc < 4; ++fc) {
      long col = col0 + fc * 16 + cl;
      int mk = mrow[col];
#pragma unroll
      for (int fr = 0; fr < 8; ++fr) {
        long row = row0 + fr * 16 + l4 * 4;
#pragma unroll
        for (int r = 0; r < 4; ++r) {
          float v = mk ? acc[fr][fc][r] * scale + 1e-13f : -1e-13f;
          C[(row + r) * ldc + col] = v;
        }
      }
    }
  } else if constexpr (EPI == 1) {
    u16* C = (u16*)Cv + (long)blockIdx.z * bsC;
#pragma unroll
    for (int fc = 0; fc < 4; ++fc) {
      long col = col0 + fc * 16 + cl;
#pragma unroll
      for (int fr = 0; fr < 8; ++fr) {
        long row = row0 + fr * 16 + l4 * 4;
#pragma unroll
        for (int r = 0; r < 4; ++r) C[(row + r) * ldc + col] = f2bf(acc[fr][fc][r]);
      }
    }
  } else {
    float* C = (float*)Cv;
#pragma unroll
    for (int fc = 0; fc < 4; ++fc) {
      long col = col0 + fc * 16 + cl;
      float bj = bias[col];
#pragma unroll
      for (int fr = 0; fr < 8; ++fr) {
        long row = row0 + fr * 16 + l4 * 4;
#pragma unroll
        for (int r = 0; r < 4; ++r) C[(row + r) * ldc + col] = acc[fr][fc][r] + bj;
      }
    }
  }
}

// ---------- row softmax: read 2048 f32, write 2048 bf16 in-place ----------
__global__ __launch_bounds__(256) void softmax_rows(float* __restrict__ S) {
  const int t = threadIdx.x;
  const float* row = S + (long)blockIdx.x * 2048;
  float4 x0 = ((const float4*)row)[t];
  float4 x1 = ((const float4*)row)[256 + t];
  float m = fmaxf(fmaxf(fmaxf(x0.x, x0.y), fmaxf(x0.z, x0.w)),
                  fmaxf(fmaxf(x1.x, x1.y), fmaxf(x1.z, x1.w)));
#pragma unroll
  for (int off = 32; off; off >>= 1) m = fmaxf(m, __shfl_xor(m, off));
  __shared__ float red[8];
  if ((t & 63) == 0) red[t >> 6] = m;
  __syncthreads();
  m = fmaxf(fmaxf(red[0], red[1]), fmaxf(red[2], red[3]));
  float p[8];
  p[0] = __expf(x0.x - m); p[1] = __expf(x0.y - m);
  p[2] = __expf(x0.z - m); p[3] = __expf(x0.w - m);
  p[4] = __expf(x1.x - m); p[5] = __expf(x1.y - m);
  p[6] = __expf(x1.z - m); p[7] = __expf(x1.w - m);
  float s = ((p[0] + p[1]) + (p[2] + p[3])) + ((p[4] + p[5]) + (p[6] + p[7]));
#pragma unroll
  for (int off = 32; off; off >>= 1) s += __shfl_xor(s, off);
  if ((t & 63) == 0) red[4 + (t >> 6)] = s;
  __syncthreads();
  float inv = 1.0f / (red[4] + red[5] + red[6] + red[7]);
  u16* prow = (u16*)S + (long)blockIdx.x * 4096;
  u16x4 o0, o1;
  o0[0] = f2bf(p[0] * inv); o0[1] = f2bf(p[1] * inv);
  o0[2] = f2bf(p[2] * inv); o0[3] = f2bf(p[3] * inv);
  o1[0] = f2bf(p[4] * inv); o1[1] = f2bf(p[5] * inv);
  o1[2] = f2bf(p[6] * inv); o1[3] = f2bf(p[7] * inv);
  *(u16x4*)(prow + 4 * t) = o0;
  *(u16x4*)(prow + 1024 + 4 * t) = o1;
}

// ---------- launcher ----------
extern "C" void kernel_launch(void* const* d_in, const int* in_sizes, int n_in,
                              void* d_out, int out_size, void* d_ws, size_t ws_size,
                              hipStream_t stream) {
  const float* Q = (const float*)d_in[0];
  const float* K = (const float*)d_in[1];
  const float* V = (const float*)d_in[2];
  const int* mask = (const int*)d_in[3];
  const float* W = (const float*)d_in[4];
  const float* bias = (const float*)d_in[5];

  const long NQ = 16L * 2048 * 1024;
  u16* Qb = (u16*)d_ws;
  u16* Kb = Qb + NQ;
  u16* Vb = Kb + NQ;
  u16* Wb = Vb + NQ;
  float* S = (float*)(Wb + 1024L * 1024);  // [16][2048][2048] f32; P bf16 in-place
  u16* R = Qb;                             // alias: Qb dead after GEMM1

  cvt_f32_bf16<<<2048, 256, 0, stream>>>(Q, Qb, NQ);
  cvt_f32_bf16<<<2048, 256, 0, stream>>>(K, Kb, NQ);
  cvt_f32_bf16<<<2048, 256, 0, stream>>>(V, Vb, NQ);
  cvt_f32_bf16<<<512, 256, 0, stream>>>(W, Wb, 1024L * 1024);

  // S = QK^T * scale (+1e-13), masked cols -> -1e-13   [2048 x 2048 x 1024] x16
  gemm256<0><<<dim3(8, 8, 16), 512, 131072, stream>>>(
      Qb, 1024, 2048L * 1024, Kb, 1024, 2048L * 1024,
      S, 2048, 2048L * 2048, 1024, mask, 0.03125f, nullptr);

  softmax_rows<<<32768, 256, 0, stream>>>(S);

  // R = P V^T   [2048 x 1024 x 2048] x16 ; P lda 4096 (bf16 inside f32 rows)
  gemm256<1><<<dim3(8, 4, 16), 512, 131072, stream>>>(
      (const u16*)S, 4096, 2048L * 4096, Vb, 2048, 1024L * 2048,
      R, 1024, 2048L * 1024, 2048, nullptr, 1.f, nullptr);

  // out = R W^T + bias   [32768 x 1024 x 1024]
  gemm256<2><<<dim3(128, 4, 1), 512, 131072, stream>>>(
      R, 1024, 0, Wb, 1024, 0,
      d_out, 1024, 0, 1024, nullptr, 1.f, bias);
}